// Round 8
// baseline (343.177 us; speedup 1.0000x reference)
//
#include <hip/hip_runtime.h>
#include <hip/hip_bf16.h>

// Problem constants
static constexpr int N_   = 100000;
static constexpr int E_   = 1600000;
static constexpr int FIN_ = 128;
static constexpr int DIM_ = 32;
static constexpr int NC_  = 40;
static constexpr int NB_BKT = (N_ + 127) / 128;   // 782 buckets of 128 dst nodes
static constexpr int NCHUNK = 256;                // edge chunks
static constexpr int EPC    = E_ / NCHUNK;        // 6250 edges per chunk (exact)
static constexpr int NB64   = (N_ + 63) / 64;     // 1563 dense blocks (64 nodes) -> pad
static constexpr int NB64P  = 1564;               // padded to cover 100096 rows
static constexpr int CS_NB  = (NB_BKT + 7) / 8;   // 98 colscan blocks

__device__ __forceinline__ int edge_at(const void* e, int is64, long long i) {
    return is64 ? (int)((const long long*)e)[i] : ((const int*)e)[i];
}

__device__ __forceinline__ float bflo(unsigned u) { return __uint_as_float(u << 16); }
__device__ __forceinline__ float bfhi(unsigned u) { return __uint_as_float(u & 0xffff0000u); }

__device__ __forceinline__ unsigned pack2bf(float a, float b) {
    __hip_bfloat16 ha = __float2bfloat16(a), hb = __float2bfloat16(b);
    unsigned ua = *(const unsigned short*)&ha, ub = *(const unsigned short*)&hb;
    return ua | (ub << 16);
}

// Per-block edge dtype detection (reference says int64; JAX x64-off gives int32;
// int32 read as int64 -> garbage high words -> out of [0,N) w.h.p.)
#define DETECT_FLAG(edge, sflag)                                        \
    if (threadIdx.x < 64) {                                             \
        const long long* p_ = (const long long*)(edge);                 \
        long long v_ = p_[threadIdx.x];                                 \
        bool bad_ = (v_ < 0 || v_ >= (long long)N_);                    \
        unsigned long long m_ = __ballot(bad_);                         \
        if (threadIdx.x == 0) sflag = (m_ == 0ull) ? 1 : 0;             \
    }                                                                   \
    __syncthreads();

// ---------------------------------------------------------------------------
// Dense dot helper (2-row tile): acc[i] (cols d0..d0+3) += A-rows {nq,nq+32} @ W.
// All LDS reads are conflict-free b128: W row stride 32 (8 distinct 16B slots,
// broadcast across same-dq lanes); A row stride 36, bank-start 4*nq.
// ---------------------------------------------------------------------------
__device__ __forceinline__ void stage_acc2(const float* __restrict__ Asm,
                                           const float* __restrict__ Wsm,
                                           int nq, int d0, float4 acc[2]) {
#pragma unroll
    for (int kc = 0; kc < 8; ++kc) {
        float4 w0 = *(const float4*)&Wsm[(kc * 4 + 0) * 32 + d0];
        float4 w1 = *(const float4*)&Wsm[(kc * 4 + 1) * 32 + d0];
        float4 w2 = *(const float4*)&Wsm[(kc * 4 + 2) * 32 + d0];
        float4 w3 = *(const float4*)&Wsm[(kc * 4 + 3) * 32 + d0];
#pragma unroll
        for (int i = 0; i < 2; ++i) {
            float4 a = *(const float4*)&Asm[(nq + 32 * i) * 36 + kc * 4];
            acc[i].x += a.x * w0.x + a.y * w1.x + a.z * w2.x + a.w * w3.x;
            acc[i].y += a.x * w0.y + a.y * w1.y + a.z * w2.y + a.w * w3.y;
            acc[i].z += a.x * w0.z + a.y * w1.z + a.z * w2.z + a.w * w3.z;
            acc[i].w += a.x * w0.w + a.y * w1.w + a.z * w2.w + a.w * w3.w;
        }
    }
}

// ---------------------------------------------------------------------------
// Build 1: per-chunk bucket histogram in LDS -> ghist[b][k]
// ---------------------------------------------------------------------------
__global__ __launch_bounds__(256) void chist_kernel(const void* __restrict__ edge,
                                                    int* __restrict__ ghist) {
    __shared__ int lh[NB_BKT];
    __shared__ int sflag;
    DETECT_FLAG(edge, sflag)
    for (int i = threadIdx.x; i < NB_BKT; i += 256) lh[i] = 0;
    __syncthreads();
    int f = sflag;
    int b = blockIdx.x;
    int end = b * EPC + EPC;
    for (int e = b * EPC + threadIdx.x; e < end; e += 256) {
        int d = edge_at(edge, f, (long long)E_ + e);
        atomicAdd(&lh[d >> 7], 1);           // LDS int atomic
    }
    __syncthreads();
    for (int i = threadIdx.x; i < NB_BKT; i += 256) ghist[b * NB_BKT + i] = lh[i];
}

// ---------------------------------------------------------------------------
// Build 2: column scans -> gcur (chunk-major), bcnt; ticket block -> bbase+offs[N]
// ---------------------------------------------------------------------------
__global__ __launch_bounds__(256) void colscan_kernel(const int* __restrict__ ghist,
                                                      int* __restrict__ gcur,
                                                      int* __restrict__ bcnt,
                                                      int* __restrict__ bbase,
                                                      int* __restrict__ offs,
                                                      int* __restrict__ done) {
    __shared__ int tile[256 * 9];
    __shared__ int a[256];
    __shared__ int lastFlag;
    int tid = threadIdx.x;
    int k0 = blockIdx.x * 8;

    {
        int kk = tid & 7, r0 = tid >> 3;
        for (int p = 0; p < 8; ++p) {
            int b = r0 + p * 32;
            int k = k0 + kk;
            tile[b * 9 + kk] = (k < NB_BKT) ? ghist[b * NB_BKT + k] : 0;
        }
    }
    __syncthreads();

    int c = tid >> 5, lane = tid & 31;
    int v[8]; int s = 0;
#pragma unroll
    for (int r = 0; r < 8; ++r) { v[r] = tile[(lane * 8 + r) * 9 + c]; s += v[r]; }
    int incl = s;
#pragma unroll
    for (int off = 1; off < 32; off <<= 1) {
        int u = __shfl_up(incl, off, 32);
        if (lane >= off) incl += u;
    }
    int ex = incl - s;
    int k = k0 + c;
    if (k < NB_BKT) {
        int run = ex;
#pragma unroll
        for (int r = 0; r < 8; ++r) {
            int b = lane * 8 + r;
            gcur[b * NB_BKT + k] = run;
            run += v[r];
        }
        if (lane == 31) bcnt[k] = run;
    }
    __syncthreads();
    if (tid == 0) {
        __threadfence();
        int old = atomicAdd(done, 1);
        lastFlag = (old == CS_NB - 1) ? 1 : 0;
    }
    __syncthreads();
    if (lastFlag) {
        __threadfence();
        int b4[4]; int base4 = tid * 4; int t = 0;
#pragma unroll
        for (int j = 0; j < 4; ++j) { int i = base4 + j; b4[j] = (i < NB_BKT) ? bcnt[i] : 0; t += b4[j]; }
        a[tid] = t;
        __syncthreads();
        for (int off = 1; off < 256; off <<= 1) {
            int u = a[tid] + ((tid >= off) ? a[tid - off] : 0);
            __syncthreads(); a[tid] = u; __syncthreads();
        }
        int g = a[tid] - t;
#pragma unroll
        for (int j = 0; j < 4; ++j) { int i = base4 + j; if (i < NB_BKT) bbase[i] = g; g += b4[j]; }
        if (tid == 255) offs[N_] = a[255];
    }
}

// ---------------------------------------------------------------------------
// Build 3: deterministic scatter into bucket regions
// ---------------------------------------------------------------------------
__global__ __launch_bounds__(256) void dscatter_kernel(const void* __restrict__ edge,
                                                       const int* __restrict__ bbase,
                                                       const int* __restrict__ gcur,
                                                       int* __restrict__ packed) {
    __shared__ int cur[NB_BKT];
    __shared__ int sflag;
    DETECT_FLAG(edge, sflag)
    int b = blockIdx.x, tid = threadIdx.x;
    for (int k = tid; k < NB_BKT; k += 256) cur[k] = bbase[k] + gcur[b * NB_BKT + k];
    __syncthreads();
    int f = sflag;
    int end = b * EPC + EPC;
    for (int e = b * EPC + tid; e < end; e += 256) {
        int s = edge_at(edge, f, e);
        int d = edge_at(edge, f, (long long)E_ + e);
        int pos = atomicAdd(&cur[d >> 7], 1);
        packed[pos] = s | ((d & 127) << 17);
    }
}

// ---------------------------------------------------------------------------
// Build 4: per-bucket counting sort -> offs[] + csr[]. Own small footprint.
// ---------------------------------------------------------------------------
__global__ __launch_bounds__(256) void bsort_kernel(const int* __restrict__ bcnt,
                                                    const int* __restrict__ bbase,
                                                    const int* __restrict__ packed,
                                                    int* __restrict__ offs,
                                                    int* __restrict__ csr) {
    __shared__ int c[128];
    __shared__ int cur[128];
    int tid = threadIdx.x;
    int b = blockIdx.x;
    int beg = bbase[b], cnt = bcnt[b];
    if (tid < 128) c[tid] = 0;
    __syncthreads();
    for (int i = tid; i < cnt; i += 256)
        atomicAdd(&c[packed[beg + i] >> 17], 1);
    __syncthreads();
    int myv = (tid < 128) ? c[tid] : 0;
    for (int off = 1; off < 128; off <<= 1) {
        int t = 0;
        if (tid < 128) t = c[tid] + ((tid >= off) ? c[tid - off] : 0);
        __syncthreads();
        if (tid < 128) c[tid] = t;
        __syncthreads();
    }
    if (tid < 128) {
        int ex = c[tid] - myv;
        cur[tid] = ex;
        int node = b * 128 + tid;
        if (node < N_) offs[node] = beg + ex;
    }
    __syncthreads();
    for (int i = tid; i < cnt; i += 256) {
        int v = packed[beg + i];
        int p = atomicAdd(&cur[v >> 17], 1);
        csr[beg + p] = v & 0x1FFFF;
    }
}

// ---------------------------------------------------------------------------
// proj: yh = bf16(x @ w1a). 64 nodes/block, 2n x 4d tile, 4 K-chunks of 32.
// LDS 25.6 KB (6 blocks/CU); launch_bounds(256,4) caps VGPR at 128.
// ---------------------------------------------------------------------------
__global__ __launch_bounds__(256, 4) void proj_kernel(const float* __restrict__ x,
                                                      const float* __restrict__ w,
                                                      __hip_bfloat16* __restrict__ yh) {
    __shared__ __align__(16) float wsm[FIN_ * DIM_];   // 16 KB, [k][d]
    __shared__ __align__(16) float xs[64 * 36];        // 9 KB, stride 36
    int tid = threadIdx.x;
    {
        const float4* w4 = (const float4*)w;
        float4* ws4 = (float4*)wsm;
        for (int i = tid; i < FIN_ * DIM_ / 4; i += 256) ws4[i] = w4[i];
    }
    int nodeBase = blockIdx.x * 64;
    int nq = tid >> 3, dq = tid & 7, d0 = dq * 4;
    const float4* x4 = (const float4*)x;

    float4 acc[2];
    acc[0] = make_float4(0.f, 0.f, 0.f, 0.f);
    acc[1] = make_float4(0.f, 0.f, 0.f, 0.f);

    for (int ch = 0; ch < 4; ++ch) {
        __syncthreads();   // xs reuse barrier (at ch=0: orders weight loads too)
#pragma unroll
        for (int p = 0; p < 2; ++p) {
            int idx = tid + 256 * p;
            int row = idx >> 3, c4 = idx & 7;
            int gn = nodeBase + row; if (gn >= N_) gn = N_ - 1;
            *(float4*)&xs[row * 36 + c4 * 4] = x4[(size_t)gn * 32 + ch * 8 + c4];
        }
        __syncthreads();
        stage_acc2(xs, wsm + ch * 32 * DIM_, nq, d0, acc);
    }
#pragma unroll
    for (int i = 0; i < 2; ++i) {
        int gn = nodeBase + nq + 32 * i;               // pad-safe: yh oversized
        uint2 pk;
        pk.x = pack2bf(acc[i].x, acc[i].y);
        pk.y = pack2bf(acc[i].z, acc[i].w);
        *(uint2*)((char*)yh + (size_t)gn * 64 + d0 * 2) = pk;
    }
}

// ---------------------------------------------------------------------------
// Gather: 8 lanes x 8B (uint2) per 64B row, 4-wide unroll, no atomics.
// ---------------------------------------------------------------------------
__device__ __forceinline__ void gather_row(const int* __restrict__ csr,
                                           const char* __restrict__ vb,
                                           int beg, int end, int loff,
                                           float& a0, float& a1, float& a2, float& a3) {
    int i = beg;
    for (; i + 3 < end; i += 4) {
        int s0 = csr[i], s1 = csr[i + 1], s2 = csr[i + 2], s3 = csr[i + 3];
        uint2 u0 = *(const uint2*)(vb + (((size_t)s0) << 6) + loff);
        uint2 u1 = *(const uint2*)(vb + (((size_t)s1) << 6) + loff);
        uint2 u2 = *(const uint2*)(vb + (((size_t)s2) << 6) + loff);
        uint2 u3 = *(const uint2*)(vb + (((size_t)s3) << 6) + loff);
        a0 += (bflo(u0.x) + bflo(u1.x)) + (bflo(u2.x) + bflo(u3.x));
        a1 += (bfhi(u0.x) + bfhi(u1.x)) + (bfhi(u2.x) + bfhi(u3.x));
        a2 += (bflo(u0.y) + bflo(u1.y)) + (bflo(u2.y) + bflo(u3.y));
        a3 += (bfhi(u0.y) + bfhi(u1.y)) + (bfhi(u2.y) + bfhi(u3.y));
    }
    for (; i < end; ++i) {
        int s0 = csr[i];
        uint2 u0 = *(const uint2*)(vb + (((size_t)s0) << 6) + loff);
        a0 += bflo(u0.x); a1 += bfhi(u0.x); a2 += bflo(u0.y); a3 += bfhi(u0.y);
    }
}

// ---------------------------------------------------------------------------
// Gather + u: u[node][d] = relu(agg + self + bias). Zero LDS, low VGPR.
// ---------------------------------------------------------------------------
__global__ __launch_bounds__(256) void gathu_kernel(const int* __restrict__ offs,
                                                    const int* __restrict__ csr,
                                                    const __hip_bfloat16* __restrict__ vh,
                                                    const float* __restrict__ bias,
                                                    float* __restrict__ u) {
    int tid = threadIdx.x;
    int nl = tid >> 3, slot = tid & 7;
    int node = blockIdx.x * 32 + nl;
    int beg = offs[node], end = offs[node + 1];
    float a0 = 0.f, a1 = 0.f, a2 = 0.f, a3 = 0.f;
    gather_row(csr, (const char*)vh, beg, end, slot << 3, a0, a1, a2, a3);
    uint2 uy = *(const uint2*)((const char*)vh + (((size_t)node) << 6) + (slot << 3));
    float4 bv = ((const float4*)bias)[slot];
    float4 r;
    r.x = fmaxf(a0 + bflo(uy.x) + bv.x, 0.f);
    r.y = fmaxf(a1 + bfhi(uy.x) + bv.y, 0.f);
    r.z = fmaxf(a2 + bflo(uy.y) + bv.z, 0.f);
    r.w = fmaxf(a3 + bfhi(uy.y) + bv.w, 0.f);
    ((float4*)u)[(size_t)blockIdx.x * 256 + tid] = r;
}

// ---------------------------------------------------------------------------
// Dense MLP 1: 64 nodes/block, 2n x 4d register tiles, in-place A.
// u -> hb=bn1(relu(u@w1b+b1b)) -> zh=bf16(hb@w2a). LDS 17.4 KB.
// ---------------------------------------------------------------------------
__global__ __launch_bounds__(256, 4) void mlp1_kernel(const float* __restrict__ u,
                                                      const float* __restrict__ w1b,
                                                      const float* __restrict__ b1b,
                                                      const float* __restrict__ g1,
                                                      const float* __restrict__ be1,
                                                      const float* __restrict__ m1,
                                                      const float* __restrict__ v1,
                                                      const float* __restrict__ w2a,
                                                      __hip_bfloat16* __restrict__ zh) {
    __shared__ __align__(16) float A[64 * 36];
    __shared__ float w1s[DIM_ * DIM_];
    __shared__ float w2s[DIM_ * DIM_];
    int tid = threadIdx.x;
    for (int i = tid; i < DIM_ * DIM_; i += 256) { w1s[i] = w1b[i]; w2s[i] = w2a[i]; }
    {
        const float4* u4 = (const float4*)u + (size_t)blockIdx.x * 512;
#pragma unroll
        for (int p = 0; p < 2; ++p) {
            int idx = tid + 256 * p;
            int n = idx >> 3, sl = idx & 7;
            *(float4*)&A[n * 36 + sl * 4] = u4[idx];
        }
    }
    __syncthreads();

    int nq = tid >> 3, dq = tid & 7, d0 = dq * 4;

    // per-col-quad BN constants
    float4 gq = *(const float4*)&g1[d0];
    float4 vq = *(const float4*)&v1[d0];
    float4 bq = *(const float4*)&be1[d0];
    float4 mq = *(const float4*)&m1[d0];
    float4 sc, sh;
    sc.x = gq.x * rsqrtf(vq.x + 1e-5f); sc.y = gq.y * rsqrtf(vq.y + 1e-5f);
    sc.z = gq.z * rsqrtf(vq.z + 1e-5f); sc.w = gq.w * rsqrtf(vq.w + 1e-5f);
    sh.x = bq.x - mq.x * sc.x; sh.y = bq.y - mq.y * sc.y;
    sh.z = bq.z - mq.z * sc.z; sh.w = bq.w - mq.w * sc.w;

    // stage 1: hb = bn1(relu(u @ w1b + b1b)) -> regs -> in-place A
    float4 h[2];
    {
        float4 bb = *(const float4*)&b1b[d0];
        float4 acc[2] = { bb, bb };
        stage_acc2(A, w1s, nq, d0, acc);
#pragma unroll
        for (int i = 0; i < 2; ++i) {
            h[i].x = fmaxf(acc[i].x, 0.f) * sc.x + sh.x;
            h[i].y = fmaxf(acc[i].y, 0.f) * sc.y + sh.y;
            h[i].z = fmaxf(acc[i].z, 0.f) * sc.z + sh.z;
            h[i].w = fmaxf(acc[i].w, 0.f) * sc.w + sh.w;
        }
    }
    __syncthreads();   // all stage-1 reads of A done
#pragma unroll
    for (int i = 0; i < 2; ++i) *(float4*)&A[(nq + 32 * i) * 36 + d0] = h[i];
    __syncthreads();

    // stage 2: z = hb @ w2a -> bf16
    {
        float4 acc[2];
        acc[0] = make_float4(0.f, 0.f, 0.f, 0.f);
        acc[1] = make_float4(0.f, 0.f, 0.f, 0.f);
        stage_acc2(A, w2s, nq, d0, acc);
#pragma unroll
        for (int i = 0; i < 2; ++i) {
            int gn = blockIdx.x * 64 + nq + 32 * i;   // pad-safe: zh oversized
            uint2 pk;
            pk.x = pack2bf(acc[i].x, acc[i].y);
            pk.y = pack2bf(acc[i].z, acc[i].w);
            *(uint2*)((char*)zh + (size_t)gn * 64 + d0 * 2) = pk;
        }
    }
}

// ---------------------------------------------------------------------------
// Dense MLP 2 + head: 64 nodes/block, 2n x 4d, in-place A. LDS 22.5 KB.
// u2 -> hb=bn2(u2@w2b+b2b) -> f=relu(hb@fc1w+f1b) -> logits -> log_softmax.
// ---------------------------------------------------------------------------
__global__ __launch_bounds__(256, 4) void mlp2_kernel(const float* __restrict__ u,
                                                      const float* __restrict__ w2b,
                                                      const float* __restrict__ b2b,
                                                      const float* __restrict__ g2,
                                                      const float* __restrict__ be2,
                                                      const float* __restrict__ m2,
                                                      const float* __restrict__ v2,
                                                      const float* __restrict__ f1w,
                                                      const float* __restrict__ f1b,
                                                      const float* __restrict__ f2w,
                                                      const float* __restrict__ f2b,
                                                      float* __restrict__ out) {
    __shared__ __align__(16) float A[64 * 36];
    __shared__ float wA[DIM_ * DIM_];
    __shared__ float wB[DIM_ * DIM_];
    __shared__ float wC[DIM_ * NC_];   // fc2 weights [32][40]
    int tid = threadIdx.x;
    for (int i = tid; i < DIM_ * DIM_; i += 256) { wA[i] = w2b[i]; wB[i] = f1w[i]; }
    for (int i = tid; i < DIM_ * NC_; i += 256) wC[i] = f2w[i];
    {
        const float4* u4 = (const float4*)u + (size_t)blockIdx.x * 512;
#pragma unroll
        for (int p = 0; p < 2; ++p) {
            int idx = tid + 256 * p;
            int n = idx >> 3, sl = idx & 7;
            *(float4*)&A[n * 36 + sl * 4] = u4[idx];
        }
    }
    __syncthreads();

    int nq = tid >> 3, dq = tid & 7, d0 = dq * 4;

    float4 gq = *(const float4*)&g2[d0];
    float4 vq = *(const float4*)&v2[d0];
    float4 bq = *(const float4*)&be2[d0];
    float4 mq = *(const float4*)&m2[d0];
    float4 sc, sh;
    sc.x = gq.x * rsqrtf(vq.x + 1e-5f); sc.y = gq.y * rsqrtf(vq.y + 1e-5f);
    sc.z = gq.z * rsqrtf(vq.z + 1e-5f); sc.w = gq.w * rsqrtf(vq.w + 1e-5f);
    sh.x = bq.x - mq.x * sc.x; sh.y = bq.y - mq.y * sc.y;
    sh.z = bq.z - mq.z * sc.z; sh.w = bq.w - mq.w * sc.w;

    // stage 1: hb = bn2(u2 @ w2b + b2b) -> regs -> in-place A  (no relu pre-bn)
    {
        float4 bb = *(const float4*)&b2b[d0];
        float4 acc[2] = { bb, bb };
        stage_acc2(A, wA, nq, d0, acc);
        float4 h[2];
#pragma unroll
        for (int i = 0; i < 2; ++i) {
            h[i].x = acc[i].x * sc.x + sh.x;
            h[i].y = acc[i].y * sc.y + sh.y;
            h[i].z = acc[i].z * sc.z + sh.z;
            h[i].w = acc[i].w * sc.w + sh.w;
        }
        __syncthreads();
#pragma unroll
        for (int i = 0; i < 2; ++i) *(float4*)&A[(nq + 32 * i) * 36 + d0] = h[i];
        __syncthreads();
    }

    // stage 2: f = relu(hb @ fc1w + f1b) -> regs -> in-place A
    {
        float4 bb = *(const float4*)&f1b[d0];
        float4 acc[2] = { bb, bb };
        stage_acc2(A, wB, nq, d0, acc);
        float4 h[2];
#pragma unroll
        for (int i = 0; i < 2; ++i) {
            h[i].x = fmaxf(acc[i].x, 0.f); h[i].y = fmaxf(acc[i].y, 0.f);
            h[i].z = fmaxf(acc[i].z, 0.f); h[i].w = fmaxf(acc[i].w, 0.f);
        }
        __syncthreads();
#pragma unroll
        for (int i = 0; i < 2; ++i) *(float4*)&A[(nq + 32 * i) * 36 + d0] = h[i];
        __syncthreads();
    }

    // stage 3: logits (cols d0..d0+3 and 32+dq) + log_softmax
    {
        float4 bb = *(const float4*)&f2b[d0];
        float be = f2b[32 + dq];
        float4 acc[2] = { bb, bb };
        float acce[2] = { be, be };
#pragma unroll
        for (int kc = 0; kc < 8; ++kc) {
            float4 w0 = *(const float4*)&wC[(kc * 4 + 0) * NC_ + d0];
            float4 w1 = *(const float4*)&wC[(kc * 4 + 1) * NC_ + d0];
            float4 w2 = *(const float4*)&wC[(kc * 4 + 2) * NC_ + d0];
            float4 w3 = *(const float4*)&wC[(kc * 4 + 3) * NC_ + d0];
            float e0 = wC[(kc * 4 + 0) * NC_ + 32 + dq];
            float e1 = wC[(kc * 4 + 1) * NC_ + 32 + dq];
            float e2 = wC[(kc * 4 + 2) * NC_ + 32 + dq];
            float e3 = wC[(kc * 4 + 3) * NC_ + 32 + dq];
#pragma unroll
            for (int i = 0; i < 2; ++i) {
                float4 a = *(const float4*)&A[(nq + 32 * i) * 36 + kc * 4];
                acc[i].x += a.x * w0.x + a.y * w1.x + a.z * w2.x + a.w * w3.x;
                acc[i].y += a.x * w0.y + a.y * w1.y + a.z * w2.y + a.w * w3.y;
                acc[i].z += a.x * w0.z + a.y * w1.z + a.z * w2.z + a.w * w3.z;
                acc[i].w += a.x * w0.w + a.y * w1.w + a.z * w2.w + a.w * w3.w;
                acce[i]  += a.x * e0   + a.y * e1   + a.z * e2   + a.w * e3;
            }
        }
#pragma unroll
        for (int i = 0; i < 2; ++i) {
            float mx = fmaxf(fmaxf(fmaxf(acc[i].x, acc[i].y), fmaxf(acc[i].z, acc[i].w)), acce[i]);
#pragma unroll
            for (int off = 1; off < 8; off <<= 1) mx = fmaxf(mx, __shfl_xor(mx, off, 8));
            float se = __expf(acc[i].x - mx) + __expf(acc[i].y - mx)
                     + __expf(acc[i].z - mx) + __expf(acc[i].w - mx)
                     + __expf(acce[i] - mx);
#pragma unroll
            for (int off = 1; off < 8; off <<= 1) se += __shfl_xor(se, off, 8);
            float lse = mx + __logf(se);
            int gn = blockIdx.x * 64 + nq + 32 * i;
            if (gn < N_) {
                float4 o;
                o.x = acc[i].x - lse; o.y = acc[i].y - lse;
                o.z = acc[i].z - lse; o.w = acc[i].w - lse;
                *(float4*)&out[(size_t)gn * NC_ + d0] = o;
                out[(size_t)gn * NC_ + 32 + dq] = acce[i] - lse;
            }
        }
    }
}

// ---------------------------------------------------------------------------
extern "C" void kernel_launch(void* const* d_in, const int* in_sizes, int n_in,
                              void* d_out, int out_size, void* d_ws, size_t ws_size,
                              hipStream_t stream) {
    const float* x   = (const float*)d_in[0];
    const void*  edg = d_in[1];
    const float* w1a = (const float*)d_in[2];
    const float* b1a = (const float*)d_in[3];
    const float* w1b = (const float*)d_in[4];
    const float* b1b = (const float*)d_in[5];
    const float* w2a = (const float*)d_in[6];
    const float* b2a = (const float*)d_in[7];
    const float* w2b = (const float*)d_in[8];
    const float* b2b = (const float*)d_in[9];
    const float* g1  = (const float*)d_in[10];
    const float* be1 = (const float*)d_in[11];
    const float* m1  = (const float*)d_in[12];
    const float* v1  = (const float*)d_in[13];
    const float* g2  = (const float*)d_in[14];
    const float* be2 = (const float*)d_in[15];
    const float* m2  = (const float*)d_in[16];
    const float* v2  = (const float*)d_in[17];
    const float* f1w = (const float*)d_in[18];
    const float* f1b = (const float*)d_in[19];
    const float* f2w = (const float*)d_in[20];
    const float* f2b = (const float*)d_in[21];
    float* out = (float*)d_out;

    // Workspace layout (byte offsets; yh/zh/u padded to 100096 rows)
    char* ws = (char*)d_ws;
    int* done   = (int*)ws;                      // 4 B (memset each launch)
    int* bcnt   = (int*)(ws + 256);
    int* bbase  = (int*)(ws + 3584);
    int* ghist  = (int*)(ws + 6912);             // 256*782 ints
    int* gcur   = (int*)(ws + 807680);           // 256*782 ints
    int* offs   = (int*)(ws + 1608448);          // N+1 ints (pad to 400384)
    int* packed = (int*)(ws + 2008832);          // E ints
    int* csr    = (int*)(ws + 8408832);          // E ints
    __hip_bfloat16* yh = (__hip_bfloat16*)(ws + 14808832);  // 100096*32 bf16
    __hip_bfloat16* zh = (__hip_bfloat16*)(ws + 21214976);  // 100096*32 bf16
    float* u    = (float*)(ws + 27621120);       // 100096*32 f32

    hipMemsetAsync(done, 0, 4, stream);

    // ---- Build per-node CSR (deterministic, no global atomics) ----
    chist_kernel<<<NCHUNK, 256, 0, stream>>>(edg, ghist);
    colscan_kernel<<<CS_NB, 256, 0, stream>>>(ghist, gcur, bcnt, bbase, offs, done);
    dscatter_kernel<<<NCHUNK, 256, 0, stream>>>(edg, bbase, gcur, packed);
    bsort_kernel<<<NB_BKT, 256, 0, stream>>>(bcnt, bbase, packed, offs, csr);

    // ---- proj (64-node blocks, own regalloc) ----
    proj_kernel<<<NB64P, 256, 0, stream>>>(x, w1a, yh);

    // ---- Layer 1 ----
    gathu_kernel<<<N_ / 32, 256, 0, stream>>>(offs, csr, yh, b1a, u);
    mlp1_kernel<<<NB64P, 256, 0, stream>>>(u, w1b, b1b, g1, be1, m1, v1, w2a, zh);

    // ---- Layer 2 + head ----
    gathu_kernel<<<N_ / 32, 256, 0, stream>>>(offs, csr, zh, b2a, u);
    mlp2_kernel<<<NB64P, 256, 0, stream>>>(u, w2b, b2b, g2, be2, m2, v2,
                                           f1w, f1b, f2w, f2b, out);
}

// Round 9
// 288.099 us; speedup vs baseline: 1.1912x; 1.1912x over previous
//
#include <hip/hip_runtime.h>
#include <hip/hip_bf16.h>

// Problem constants
static constexpr int N_   = 100000;
static constexpr int E_   = 1600000;
static constexpr int FIN_ = 128;
static constexpr int DIM_ = 32;
static constexpr int NC_  = 40;
static constexpr int NB_BKT = (N_ + 127) / 128;   // 782 buckets of 128 dst nodes
static constexpr int NCHUNK = 256;                // edge chunks
static constexpr int EPC    = E_ / NCHUNK;        // 6250 edges per chunk (exact)
static constexpr int NB64P  = 1564;               // 64-node dense blocks (100096 rows)
static constexpr int CS_NB  = (NB_BKT + 7) / 8;   // 98 colscan blocks

__device__ __forceinline__ int edge_at(const void* e, int is64, long long i) {
    return is64 ? (int)((const long long*)e)[i] : ((const int*)e)[i];
}

__device__ __forceinline__ float bflo(unsigned u) { return __uint_as_float(u << 16); }
__device__ __forceinline__ float bfhi(unsigned u) { return __uint_as_float(u & 0xffff0000u); }

__device__ __forceinline__ unsigned pack2bf(float a, float b) {
    __hip_bfloat16 ha = __float2bfloat16(a), hb = __float2bfloat16(b);
    unsigned ua = *(const unsigned short*)&ha, ub = *(const unsigned short*)&hb;
    return ua | (ub << 16);
}

// Per-block edge dtype detection (reference says int64; JAX x64-off gives int32;
// int32 read as int64 -> garbage high words -> out of [0,N) w.h.p.)
#define DETECT_FLAG(edge, sflag)                                        \
    if (threadIdx.x < 64) {                                             \
        const long long* p_ = (const long long*)(edge);                 \
        long long v_ = p_[threadIdx.x];                                 \
        bool bad_ = (v_ < 0 || v_ >= (long long)N_);                    \
        unsigned long long m_ = __ballot(bad_);                         \
        if (threadIdx.x == 0) sflag = (m_ == 0ull) ? 1 : 0;             \
    }                                                                   \
    __syncthreads();

// ---------------------------------------------------------------------------
// Dense dot helper (2-row tile): acc[i] (cols d0..d0+3) += A-rows {nq,nq+32} @ W.
// All LDS reads are conflict-free b128: W row stride 32 (8 distinct 16B slots,
// broadcast across same-dq lanes); A row stride 36, bank-start 4*nq.
// ---------------------------------------------------------------------------
__device__ __forceinline__ void stage_acc2(const float* __restrict__ Asm,
                                           const float* __restrict__ Wsm,
                                           int nq, int d0, float4 acc[2]) {
#pragma unroll
    for (int kc = 0; kc < 8; ++kc) {
        float4 w0 = *(const float4*)&Wsm[(kc * 4 + 0) * 32 + d0];
        float4 w1 = *(const float4*)&Wsm[(kc * 4 + 1) * 32 + d0];
        float4 w2 = *(const float4*)&Wsm[(kc * 4 + 2) * 32 + d0];
        float4 w3 = *(const float4*)&Wsm[(kc * 4 + 3) * 32 + d0];
#pragma unroll
        for (int i = 0; i < 2; ++i) {
            float4 a = *(const float4*)&Asm[(nq + 32 * i) * 36 + kc * 4];
            acc[i].x += a.x * w0.x + a.y * w1.x + a.z * w2.x + a.w * w3.x;
            acc[i].y += a.x * w0.y + a.y * w1.y + a.z * w2.y + a.w * w3.y;
            acc[i].z += a.x * w0.z + a.y * w1.z + a.z * w2.z + a.w * w3.z;
            acc[i].w += a.x * w0.w + a.y * w1.w + a.z * w2.w + a.w * w3.w;
        }
    }
}

// ---------------------------------------------------------------------------
// Build 1: per-chunk bucket histogram in LDS -> ghist[b][k]
// ---------------------------------------------------------------------------
__global__ __launch_bounds__(256) void chist_kernel(const void* __restrict__ edge,
                                                    int* __restrict__ ghist) {
    __shared__ int lh[NB_BKT];
    __shared__ int sflag;
    DETECT_FLAG(edge, sflag)
    for (int i = threadIdx.x; i < NB_BKT; i += 256) lh[i] = 0;
    __syncthreads();
    int f = sflag;
    int b = blockIdx.x;
    int end = b * EPC + EPC;
    for (int e = b * EPC + threadIdx.x; e < end; e += 256) {
        int d = edge_at(edge, f, (long long)E_ + e);
        atomicAdd(&lh[d >> 7], 1);           // LDS int atomic
    }
    __syncthreads();
    for (int i = threadIdx.x; i < NB_BKT; i += 256) ghist[b * NB_BKT + i] = lh[i];
}

// ---------------------------------------------------------------------------
// Build 2: column scans -> gcur (chunk-major), bcnt; ticket block -> bbase+offs[N]
// ---------------------------------------------------------------------------
__global__ __launch_bounds__(256) void colscan_kernel(const int* __restrict__ ghist,
                                                      int* __restrict__ gcur,
                                                      int* __restrict__ bcnt,
                                                      int* __restrict__ bbase,
                                                      int* __restrict__ offs,
                                                      int* __restrict__ done) {
    __shared__ int tile[256 * 9];
    __shared__ int a[256];
    __shared__ int lastFlag;
    int tid = threadIdx.x;
    int k0 = blockIdx.x * 8;

    {
        int kk = tid & 7, r0 = tid >> 3;
        for (int p = 0; p < 8; ++p) {
            int b = r0 + p * 32;
            int k = k0 + kk;
            tile[b * 9 + kk] = (k < NB_BKT) ? ghist[b * NB_BKT + k] : 0;
        }
    }
    __syncthreads();

    int c = tid >> 5, lane = tid & 31;
    int v[8]; int s = 0;
#pragma unroll
    for (int r = 0; r < 8; ++r) { v[r] = tile[(lane * 8 + r) * 9 + c]; s += v[r]; }
    int incl = s;
#pragma unroll
    for (int off = 1; off < 32; off <<= 1) {
        int u = __shfl_up(incl, off, 32);
        if (lane >= off) incl += u;
    }
    int ex = incl - s;
    int k = k0 + c;
    if (k < NB_BKT) {
        int run = ex;
#pragma unroll
        for (int r = 0; r < 8; ++r) {
            int b = lane * 8 + r;
            gcur[b * NB_BKT + k] = run;
            run += v[r];
        }
        if (lane == 31) bcnt[k] = run;
    }
    __syncthreads();
    if (tid == 0) {
        __threadfence();
        int old = atomicAdd(done, 1);
        lastFlag = (old == CS_NB - 1) ? 1 : 0;
    }
    __syncthreads();
    if (lastFlag) {
        __threadfence();
        int b4[4]; int base4 = tid * 4; int t = 0;
#pragma unroll
        for (int j = 0; j < 4; ++j) { int i = base4 + j; b4[j] = (i < NB_BKT) ? bcnt[i] : 0; t += b4[j]; }
        a[tid] = t;
        __syncthreads();
        for (int off = 1; off < 256; off <<= 1) {
            int u = a[tid] + ((tid >= off) ? a[tid - off] : 0);
            __syncthreads(); a[tid] = u; __syncthreads();
        }
        int g = a[tid] - t;
#pragma unroll
        for (int j = 0; j < 4; ++j) { int i = base4 + j; if (i < NB_BKT) bbase[i] = g; g += b4[j]; }
        if (tid == 255) offs[N_] = a[255];
    }
}

// ---------------------------------------------------------------------------
// Build 3: deterministic scatter into bucket regions
// ---------------------------------------------------------------------------
__global__ __launch_bounds__(256) void dscatter_kernel(const void* __restrict__ edge,
                                                       const int* __restrict__ bbase,
                                                       const int* __restrict__ gcur,
                                                       int* __restrict__ packed) {
    __shared__ int cur[NB_BKT];
    __shared__ int sflag;
    DETECT_FLAG(edge, sflag)
    int b = blockIdx.x, tid = threadIdx.x;
    for (int k = tid; k < NB_BKT; k += 256) cur[k] = bbase[k] + gcur[b * NB_BKT + k];
    __syncthreads();
    int f = sflag;
    int end = b * EPC + EPC;
    for (int e = b * EPC + tid; e < end; e += 256) {
        int s = edge_at(edge, f, e);
        int d = edge_at(edge, f, (long long)E_ + e);
        int pos = atomicAdd(&cur[d >> 7], 1);
        packed[pos] = s | ((d & 127) << 17);
    }
}

// ---------------------------------------------------------------------------
// Build 4: per-bucket counting sort -> offs[] + csr[]. Own small footprint.
// ---------------------------------------------------------------------------
__global__ __launch_bounds__(256) void bsort_kernel(const int* __restrict__ bcnt,
                                                    const int* __restrict__ bbase,
                                                    const int* __restrict__ packed,
                                                    int* __restrict__ offs,
                                                    int* __restrict__ csr) {
    __shared__ int c[128];
    __shared__ int cur[128];
    int tid = threadIdx.x;
    int b = blockIdx.x;
    int beg = bbase[b], cnt = bcnt[b];
    if (tid < 128) c[tid] = 0;
    __syncthreads();
    for (int i = tid; i < cnt; i += 256)
        atomicAdd(&c[packed[beg + i] >> 17], 1);
    __syncthreads();
    int myv = (tid < 128) ? c[tid] : 0;
    for (int off = 1; off < 128; off <<= 1) {
        int t = 0;
        if (tid < 128) t = c[tid] + ((tid >= off) ? c[tid - off] : 0);
        __syncthreads();
        if (tid < 128) c[tid] = t;
        __syncthreads();
    }
    if (tid < 128) {
        int ex = c[tid] - myv;
        cur[tid] = ex;
        int node = b * 128 + tid;
        if (node < N_) offs[node] = beg + ex;
    }
    __syncthreads();
    for (int i = tid; i < cnt; i += 256) {
        int v = packed[beg + i];
        int p = atomicAdd(&cur[v >> 17], 1);
        csr[beg + p] = v & 0x1FFFF;
    }
}

// ---------------------------------------------------------------------------
// proj: yh = bf16(x @ w1a). 64 nodes/block, 2n x 4d tile, 4 K-chunks of 32.
// LDS 25.6 KB. No min-waves hint (R8's (256,4) forced VGPR=64 + scratch spill
// -> 220 MB HBM round-trip; compiler picks ~100 VGPR spill-free unhinted).
// ---------------------------------------------------------------------------
__global__ __launch_bounds__(256) void proj_kernel(const float* __restrict__ x,
                                                   const float* __restrict__ w,
                                                   __hip_bfloat16* __restrict__ yh) {
    __shared__ __align__(16) float wsm[FIN_ * DIM_];   // 16 KB, [k][d]
    __shared__ __align__(16) float xs[64 * 36];        // 9 KB, stride 36
    int tid = threadIdx.x;
    {
        const float4* w4 = (const float4*)w;
        float4* ws4 = (float4*)wsm;
        for (int i = tid; i < FIN_ * DIM_ / 4; i += 256) ws4[i] = w4[i];
    }
    int nodeBase = blockIdx.x * 64;
    int nq = tid >> 3, dq = tid & 7, d0 = dq * 4;
    const float4* x4 = (const float4*)x;

    float4 acc[2];
    acc[0] = make_float4(0.f, 0.f, 0.f, 0.f);
    acc[1] = make_float4(0.f, 0.f, 0.f, 0.f);

    for (int ch = 0; ch < 4; ++ch) {
        __syncthreads();   // xs reuse barrier (at ch=0: orders weight loads too)
#pragma unroll
        for (int p = 0; p < 2; ++p) {
            int idx = tid + 256 * p;
            int row = idx >> 3, c4 = idx & 7;
            int gn = nodeBase + row; if (gn >= N_) gn = N_ - 1;
            *(float4*)&xs[row * 36 + c4 * 4] = x4[(size_t)gn * 32 + ch * 8 + c4];
        }
        __syncthreads();
        stage_acc2(xs, wsm + ch * 32 * DIM_, nq, d0, acc);
    }
#pragma unroll
    for (int i = 0; i < 2; ++i) {
        int gn = nodeBase + nq + 32 * i;               // pad-safe: yh oversized
        uint2 pk;
        pk.x = pack2bf(acc[i].x, acc[i].y);
        pk.y = pack2bf(acc[i].z, acc[i].w);
        *(uint2*)((char*)yh + (size_t)gn * 64 + d0 * 2) = pk;
    }
}

// ---------------------------------------------------------------------------
// Gather: 8 lanes x 8B (uint2) per 64B row, 4-wide unroll, no atomics.
// ---------------------------------------------------------------------------
__device__ __forceinline__ void gather_row(const int* __restrict__ csr,
                                           const char* __restrict__ vb,
                                           int beg, int end, int loff,
                                           float& a0, float& a1, float& a2, float& a3) {
    int i = beg;
    for (; i + 3 < end; i += 4) {
        int s0 = csr[i], s1 = csr[i + 1], s2 = csr[i + 2], s3 = csr[i + 3];
        uint2 u0 = *(const uint2*)(vb + (((size_t)s0) << 6) + loff);
        uint2 u1 = *(const uint2*)(vb + (((size_t)s1) << 6) + loff);
        uint2 u2 = *(const uint2*)(vb + (((size_t)s2) << 6) + loff);
        uint2 u3 = *(const uint2*)(vb + (((size_t)s3) << 6) + loff);
        a0 += (bflo(u0.x) + bflo(u1.x)) + (bflo(u2.x) + bflo(u3.x));
        a1 += (bfhi(u0.x) + bfhi(u1.x)) + (bfhi(u2.x) + bfhi(u3.x));
        a2 += (bflo(u0.y) + bflo(u1.y)) + (bflo(u2.y) + bflo(u3.y));
        a3 += (bfhi(u0.y) + bfhi(u1.y)) + (bfhi(u2.y) + bfhi(u3.y));
    }
    for (; i < end; ++i) {
        int s0 = csr[i];
        uint2 u0 = *(const uint2*)(vb + (((size_t)s0) << 6) + loff);
        a0 += bflo(u0.x); a1 += bfhi(u0.x); a2 += bflo(u0.y); a3 += bfhi(u0.y);
    }
}

// ---------------------------------------------------------------------------
// Gather + u: u[node][d] = relu(agg + self + bias). Zero LDS, low VGPR.
// ---------------------------------------------------------------------------
__global__ __launch_bounds__(256) void gathu_kernel(const int* __restrict__ offs,
                                                    const int* __restrict__ csr,
                                                    const __hip_bfloat16* __restrict__ vh,
                                                    const float* __restrict__ bias,
                                                    float* __restrict__ u) {
    int tid = threadIdx.x;
    int nl = tid >> 3, slot = tid & 7;
    int node = blockIdx.x * 32 + nl;
    int beg = offs[node], end = offs[node + 1];
    float a0 = 0.f, a1 = 0.f, a2 = 0.f, a3 = 0.f;
    gather_row(csr, (const char*)vh, beg, end, slot << 3, a0, a1, a2, a3);
    uint2 uy = *(const uint2*)((const char*)vh + (((size_t)node) << 6) + (slot << 3));
    float4 bv = ((const float4*)bias)[slot];
    float4 r;
    r.x = fmaxf(a0 + bflo(uy.x) + bv.x, 0.f);
    r.y = fmaxf(a1 + bfhi(uy.x) + bv.y, 0.f);
    r.z = fmaxf(a2 + bflo(uy.y) + bv.z, 0.f);
    r.w = fmaxf(a3 + bfhi(uy.y) + bv.w, 0.f);
    ((float4*)u)[(size_t)blockIdx.x * 256 + tid] = r;
}

// ---------------------------------------------------------------------------
// Dense MLP 1: 64 nodes/block, 2n x 4d register tiles, in-place A.
// u -> hb=bn1(relu(u@w1b+b1b)) -> zh=bf16(hb@w2a). LDS 17.4 KB.
// ---------------------------------------------------------------------------
__global__ __launch_bounds__(256) void mlp1_kernel(const float* __restrict__ u,
                                                   const float* __restrict__ w1b,
                                                   const float* __restrict__ b1b,
                                                   const float* __restrict__ g1,
                                                   const float* __restrict__ be1,
                                                   const float* __restrict__ m1,
                                                   const float* __restrict__ v1,
                                                   const float* __restrict__ w2a,
                                                   __hip_bfloat16* __restrict__ zh) {
    __shared__ __align__(16) float A[64 * 36];
    __shared__ float w1s[DIM_ * DIM_];
    __shared__ float w2s[DIM_ * DIM_];
    int tid = threadIdx.x;
    for (int i = tid; i < DIM_ * DIM_; i += 256) { w1s[i] = w1b[i]; w2s[i] = w2a[i]; }
    {
        const float4* u4 = (const float4*)u + (size_t)blockIdx.x * 512;
#pragma unroll
        for (int p = 0; p < 2; ++p) {
            int idx = tid + 256 * p;
            int n = idx >> 3, sl = idx & 7;
            *(float4*)&A[n * 36 + sl * 4] = u4[idx];
        }
    }
    __syncthreads();

    int nq = tid >> 3, dq = tid & 7, d0 = dq * 4;

    // per-col-quad BN constants
    float4 gq = *(const float4*)&g1[d0];
    float4 vq = *(const float4*)&v1[d0];
    float4 bq = *(const float4*)&be1[d0];
    float4 mq = *(const float4*)&m1[d0];
    float4 sc, sh;
    sc.x = gq.x * rsqrtf(vq.x + 1e-5f); sc.y = gq.y * rsqrtf(vq.y + 1e-5f);
    sc.z = gq.z * rsqrtf(vq.z + 1e-5f); sc.w = gq.w * rsqrtf(vq.w + 1e-5f);
    sh.x = bq.x - mq.x * sc.x; sh.y = bq.y - mq.y * sc.y;
    sh.z = bq.z - mq.z * sc.z; sh.w = bq.w - mq.w * sc.w;

    // stage 1: hb = bn1(relu(u @ w1b + b1b)) -> regs -> in-place A
    float4 h[2];
    {
        float4 bb = *(const float4*)&b1b[d0];
        float4 acc[2] = { bb, bb };
        stage_acc2(A, w1s, nq, d0, acc);
#pragma unroll
        for (int i = 0; i < 2; ++i) {
            h[i].x = fmaxf(acc[i].x, 0.f) * sc.x + sh.x;
            h[i].y = fmaxf(acc[i].y, 0.f) * sc.y + sh.y;
            h[i].z = fmaxf(acc[i].z, 0.f) * sc.z + sh.z;
            h[i].w = fmaxf(acc[i].w, 0.f) * sc.w + sh.w;
        }
    }
    __syncthreads();   // all stage-1 reads of A done
#pragma unroll
    for (int i = 0; i < 2; ++i) *(float4*)&A[(nq + 32 * i) * 36 + d0] = h[i];
    __syncthreads();

    // stage 2: z = hb @ w2a -> bf16
    {
        float4 acc[2];
        acc[0] = make_float4(0.f, 0.f, 0.f, 0.f);
        acc[1] = make_float4(0.f, 0.f, 0.f, 0.f);
        stage_acc2(A, w2s, nq, d0, acc);
#pragma unroll
        for (int i = 0; i < 2; ++i) {
            int gn = blockIdx.x * 64 + nq + 32 * i;   // pad-safe: zh oversized
            uint2 pk;
            pk.x = pack2bf(acc[i].x, acc[i].y);
            pk.y = pack2bf(acc[i].z, acc[i].w);
            *(uint2*)((char*)zh + (size_t)gn * 64 + d0 * 2) = pk;
        }
    }
}

// ---------------------------------------------------------------------------
// Dense MLP 2 + head: 64 nodes/block, 2n x 4d, in-place A. LDS 22.5 KB.
// u2 -> hb=bn2(u2@w2b+b2b) -> f=relu(hb@fc1w+f1b) -> logits -> log_softmax.
// ---------------------------------------------------------------------------
__global__ __launch_bounds__(256) void mlp2_kernel(const float* __restrict__ u,
                                                   const float* __restrict__ w2b,
                                                   const float* __restrict__ b2b,
                                                   const float* __restrict__ g2,
                                                   const float* __restrict__ be2,
                                                   const float* __restrict__ m2,
                                                   const float* __restrict__ v2,
                                                   const float* __restrict__ f1w,
                                                   const float* __restrict__ f1b,
                                                   const float* __restrict__ f2w,
                                                   const float* __restrict__ f2b,
                                                   float* __restrict__ out) {
    __shared__ __align__(16) float A[64 * 36];
    __shared__ float wA[DIM_ * DIM_];
    __shared__ float wB[DIM_ * DIM_];
    __shared__ float wC[DIM_ * NC_];   // fc2 weights [32][40]
    int tid = threadIdx.x;
    for (int i = tid; i < DIM_ * DIM_; i += 256) { wA[i] = w2b[i]; wB[i] = f1w[i]; }
    for (int i = tid; i < DIM_ * NC_; i += 256) wC[i] = f2w[i];
    {
        const float4* u4 = (const float4*)u + (size_t)blockIdx.x * 512;
#pragma unroll
        for (int p = 0; p < 2; ++p) {
            int idx = tid + 256 * p;
            int n = idx >> 3, sl = idx & 7;
            *(float4*)&A[n * 36 + sl * 4] = u4[idx];
        }
    }
    __syncthreads();

    int nq = tid >> 3, dq = tid & 7, d0 = dq * 4;

    float4 gq = *(const float4*)&g2[d0];
    float4 vq = *(const float4*)&v2[d0];
    float4 bq = *(const float4*)&be2[d0];
    float4 mq = *(const float4*)&m2[d0];
    float4 sc, sh;
    sc.x = gq.x * rsqrtf(vq.x + 1e-5f); sc.y = gq.y * rsqrtf(vq.y + 1e-5f);
    sc.z = gq.z * rsqrtf(vq.z + 1e-5f); sc.w = gq.w * rsqrtf(vq.w + 1e-5f);
    sh.x = bq.x - mq.x * sc.x; sh.y = bq.y - mq.y * sc.y;
    sh.z = bq.z - mq.z * sc.z; sh.w = bq.w - mq.w * sc.w;

    // stage 1: hb = bn2(u2 @ w2b + b2b) -> regs -> in-place A  (no relu pre-bn)
    {
        float4 bb = *(const float4*)&b2b[d0];
        float4 acc[2] = { bb, bb };
        stage_acc2(A, wA, nq, d0, acc);
        float4 h[2];
#pragma unroll
        for (int i = 0; i < 2; ++i) {
            h[i].x = acc[i].x * sc.x + sh.x;
            h[i].y = acc[i].y * sc.y + sh.y;
            h[i].z = acc[i].z * sc.z + sh.z;
            h[i].w = acc[i].w * sc.w + sh.w;
        }
        __syncthreads();
#pragma unroll
        for (int i = 0; i < 2; ++i) *(float4*)&A[(nq + 32 * i) * 36 + d0] = h[i];
        __syncthreads();
    }

    // stage 2: f = relu(hb @ fc1w + f1b) -> regs -> in-place A
    {
        float4 bb = *(const float4*)&f1b[d0];
        float4 acc[2] = { bb, bb };
        stage_acc2(A, wB, nq, d0, acc);
        float4 h[2];
#pragma unroll
        for (int i = 0; i < 2; ++i) {
            h[i].x = fmaxf(acc[i].x, 0.f); h[i].y = fmaxf(acc[i].y, 0.f);
            h[i].z = fmaxf(acc[i].z, 0.f); h[i].w = fmaxf(acc[i].w, 0.f);
        }
        __syncthreads();
#pragma unroll
        for (int i = 0; i < 2; ++i) *(float4*)&A[(nq + 32 * i) * 36 + d0] = h[i];
        __syncthreads();
    }

    // stage 3: logits (cols d0..d0+3 and 32+dq) + log_softmax
    {
        float4 bb = *(const float4*)&f2b[d0];
        float be = f2b[32 + dq];
        float4 acc[2] = { bb, bb };
        float acce[2] = { be, be };
#pragma unroll
        for (int kc = 0; kc < 8; ++kc) {
            float4 w0 = *(const float4*)&wC[(kc * 4 + 0) * NC_ + d0];
            float4 w1 = *(const float4*)&wC[(kc * 4 + 1) * NC_ + d0];
            float4 w2 = *(const float4*)&wC[(kc * 4 + 2) * NC_ + d0];
            float4 w3 = *(const float4*)&wC[(kc * 4 + 3) * NC_ + d0];
            float e0 = wC[(kc * 4 + 0) * NC_ + 32 + dq];
            float e1 = wC[(kc * 4 + 1) * NC_ + 32 + dq];
            float e2 = wC[(kc * 4 + 2) * NC_ + 32 + dq];
            float e3 = wC[(kc * 4 + 3) * NC_ + 32 + dq];
#pragma unroll
            for (int i = 0; i < 2; ++i) {
                float4 a = *(const float4*)&A[(nq + 32 * i) * 36 + kc * 4];
                acc[i].x += a.x * w0.x + a.y * w1.x + a.z * w2.x + a.w * w3.x;
                acc[i].y += a.x * w0.y + a.y * w1.y + a.z * w2.y + a.w * w3.y;
                acc[i].z += a.x * w0.z + a.y * w1.z + a.z * w2.z + a.w * w3.z;
                acc[i].w += a.x * w0.w + a.y * w1.w + a.z * w2.w + a.w * w3.w;
                acce[i]  += a.x * e0   + a.y * e1   + a.z * e2   + a.w * e3;
            }
        }
#pragma unroll
        for (int i = 0; i < 2; ++i) {
            float mx = fmaxf(fmaxf(fmaxf(acc[i].x, acc[i].y), fmaxf(acc[i].z, acc[i].w)), acce[i]);
#pragma unroll
            for (int off = 1; off < 8; off <<= 1) mx = fmaxf(mx, __shfl_xor(mx, off, 8));
            float se = __expf(acc[i].x - mx) + __expf(acc[i].y - mx)
                     + __expf(acc[i].z - mx) + __expf(acc[i].w - mx)
                     + __expf(acce[i] - mx);
#pragma unroll
            for (int off = 1; off < 8; off <<= 1) se += __shfl_xor(se, off, 8);
            float lse = mx + __logf(se);
            int gn = blockIdx.x * 64 + nq + 32 * i;
            if (gn < N_) {
                float4 o;
                o.x = acc[i].x - lse; o.y = acc[i].y - lse;
                o.z = acc[i].z - lse; o.w = acc[i].w - lse;
                *(float4*)&out[(size_t)gn * NC_ + d0] = o;
                out[(size_t)gn * NC_ + 32 + dq] = acce[i] - lse;
            }
        }
    }
}

// ---------------------------------------------------------------------------
extern "C" void kernel_launch(void* const* d_in, const int* in_sizes, int n_in,
                              void* d_out, int out_size, void* d_ws, size_t ws_size,
                              hipStream_t stream) {
    const float* x   = (const float*)d_in[0];
    const void*  edg = d_in[1];
    const float* w1a = (const float*)d_in[2];
    const float* b1a = (const float*)d_in[3];
    const float* w1b = (const float*)d_in[4];
    const float* b1b = (const float*)d_in[5];
    const float* w2a = (const float*)d_in[6];
    const float* b2a = (const float*)d_in[7];
    const float* w2b = (const float*)d_in[8];
    const float* b2b = (const float*)d_in[9];
    const float* g1  = (const float*)d_in[10];
    const float* be1 = (const float*)d_in[11];
    const float* m1  = (const float*)d_in[12];
    const float* v1  = (const float*)d_in[13];
    const float* g2  = (const float*)d_in[14];
    const float* be2 = (const float*)d_in[15];
    const float* m2  = (const float*)d_in[16];
    const float* v2  = (const float*)d_in[17];
    const float* f1w = (const float*)d_in[18];
    const float* f1b = (const float*)d_in[19];
    const float* f2w = (const float*)d_in[20];
    const float* f2b = (const float*)d_in[21];
    float* out = (float*)d_out;

    // Workspace layout (byte offsets; yh/zh/u padded to 100096 rows)
    char* ws = (char*)d_ws;
    int* done   = (int*)ws;                      // 4 B (memset each launch)
    int* bcnt   = (int*)(ws + 256);
    int* bbase  = (int*)(ws + 3584);
    int* ghist  = (int*)(ws + 6912);             // 256*782 ints
    int* gcur   = (int*)(ws + 807680);           // 256*782 ints
    int* offs   = (int*)(ws + 1608448);          // N+1 ints (pad to 400384)
    int* packed = (int*)(ws + 2008832);          // E ints
    int* csr    = (int*)(ws + 8408832);          // E ints
    __hip_bfloat16* yh = (__hip_bfloat16*)(ws + 14808832);  // 100096*32 bf16
    __hip_bfloat16* zh = (__hip_bfloat16*)(ws + 21214976);  // 100096*32 bf16
    float* u    = (float*)(ws + 27621120);       // 100096*32 f32

    hipMemsetAsync(done, 0, 4, stream);

    // ---- Build per-node CSR (deterministic, no global atomics) ----
    chist_kernel<<<NCHUNK, 256, 0, stream>>>(edg, ghist);
    colscan_kernel<<<CS_NB, 256, 0, stream>>>(ghist, gcur, bcnt, bbase, offs, done);
    dscatter_kernel<<<NCHUNK, 256, 0, stream>>>(edg, bbase, gcur, packed);
    bsort_kernel<<<NB_BKT, 256, 0, stream>>>(bcnt, bbase, packed, offs, csr);

    // ---- proj (64-node blocks, own regalloc) ----
    proj_kernel<<<NB64P, 256, 0, stream>>>(x, w1a, yh);

    // ---- Layer 1 ----
    gathu_kernel<<<N_ / 32, 256, 0, stream>>>(offs, csr, yh, b1a, u);
    mlp1_kernel<<<NB64P, 256, 0, stream>>>(u, w1b, b1b, g1, be1, m1, v1, w2a, zh);

    // ---- Layer 2 + head ----
    gathu_kernel<<<N_ / 32, 256, 0, stream>>>(offs, csr, zh, b2a, u);
    mlp2_kernel<<<NB64P, 256, 0, stream>>>(u, w2b, b2b, g2, be2, m2, v2,
                                           f1w, f1b, f2w, f2b, out);
}